// Round 4
// baseline (55.840 us; speedup 1.0000x reference)
//
#include <hip/hip_runtime.h>
#include <stdint.h>

#define N_ROWS 8192
#define DIM 256

constexpr float INV_T  = 1.0f / 0.07f;
constexpr float M0     = 1.0f / 0.07f;             // fixed LSE max: |cos| <= ~1
constexpr float LOG2E  = 1.44269504088896f;
constexpr float C1     = INV_T * LOG2E;            // exp arg scale (exp2 domain)
constexpr float C0     = -M0 * LOG2E;              // exp arg bias

typedef __bf16 bf16x8 __attribute__((ext_vector_type(8)));
typedef float  f32x4  __attribute__((ext_vector_type(4)));

__device__ inline unsigned short f32_to_bf16(float f) {
    union { float f; uint32_t u; } v; v.f = f;
    uint32_t u = v.u;
    u += 0x7FFFu + ((u >> 16) & 1u);   // round-to-nearest-even
    return (unsigned short)(u >> 16);
}

// ---------------- Kernel 1: normalize rows -> bf16, l_pos ----------------
__global__ __launch_bounds__(256) void prep_kernel(
    const float* __restrict__ q, const float* __restrict__ k,
    unsigned short* __restrict__ qb, unsigned short* __restrict__ kb,
    float* __restrict__ lposT) {
    const int wid  = threadIdx.x >> 6;
    const int lane = threadIdx.x & 63;
    const int row  = blockIdx.x * 4 + wid;

    const float4 qv = *reinterpret_cast<const float4*>(q + (size_t)row * DIM + lane * 4);
    const float4 kv = *reinterpret_cast<const float4*>(k + (size_t)row * DIM + lane * 4);

    float qq = qv.x*qv.x + qv.y*qv.y + qv.z*qv.z + qv.w*qv.w;
    float kk = kv.x*kv.x + kv.y*kv.y + kv.z*kv.z + kv.w*kv.w;
    float qk = qv.x*kv.x + qv.y*kv.y + qv.z*kv.z + qv.w*kv.w;

    #pragma unroll
    for (int off = 32; off > 0; off >>= 1) {
        qq += __shfl_xor(qq, off, 64);
        kk += __shfl_xor(kk, off, 64);
        qk += __shfl_xor(qk, off, 64);
    }
    const float iq = 1.0f / sqrtf(qq);
    const float ik = 1.0f / sqrtf(kk);

    ushort4 qs, ks;
    qs.x = f32_to_bf16(qv.x * iq); qs.y = f32_to_bf16(qv.y * iq);
    qs.z = f32_to_bf16(qv.z * iq); qs.w = f32_to_bf16(qv.w * iq);
    ks.x = f32_to_bf16(kv.x * ik); ks.y = f32_to_bf16(kv.y * ik);
    ks.z = f32_to_bf16(kv.z * ik); ks.w = f32_to_bf16(kv.w * ik);
    *reinterpret_cast<ushort4*>(qb + (size_t)row * DIM + lane * 4) = qs;
    *reinterpret_cast<ushort4*>(kb + (size_t)row * DIM + lane * 4) = ks;

    if (lane == 0) lposT[row] = qk * iq * ik * INV_T;
}

// ---------------- Kernel 2: persistent K-strip GEMM + fused exp-sum ----------
// A = K rows, B = Q rows (swapped) -> D col = lane&15 = Q row (lane-local sums).
// Phase B uses the counted-vmcnt 2-barrier step (T3-min + T4): raw s_barrier,
// vmcnt(4) waits only on the PREVIOUS step's loads, never drains in-loop.
__global__ __launch_bounds__(256, 2) void gemm_lse_kernel(
    const unsigned short* __restrict__ qb, const unsigned short* __restrict__ kb,
    float* __restrict__ ps) {
    __shared__ char lds[2 * 16384 + 1024];
    char* const b0 = lds;
    char* const b1 = lds + 16384;
    float* const redS = (float*)(lds + 32768);

    const int tid   = threadIdx.x;
    const int lane  = tid & 63;
    const int wid   = tid >> 6;
    const int waveQ = wid & 1;       // Q half (B operand / D cols)
    const int waveK = wid >> 1;      // K half (A operand / D rows)
    const int g     = lane >> 4;
    const int r16   = lane & 15;
    const int xr    = r16 & 7;

    const int strip   = blockIdx.x;        // 0..7  (== XCD id by dispatch order)
    const int qtile   = blockIdx.y;        // 0..63
    const int qbase   = qtile * 128;
    const int kstrip0 = strip * 1024;

    // staging map: thread t -> row t/8, pre-swizzled 16B slot (t%8)^(row&7)
    const int srow  = tid >> 3;
    const int sslot = (tid & 7) ^ (srow & 7);
    const int ldsWaveOff = wid * 1024;     // wave-uniform LDS sub-base

    auto stage = [&](const unsigned short* base, int row0, int k0, char* dst) {
        #pragma unroll
        for (int i = 0; i < 4; ++i) {
            const unsigned short* gp = base + (size_t)(row0 + i * 32 + srow) * DIM + k0 + sslot * 8;
            __builtin_amdgcn_global_load_lds(
                (const __attribute__((address_space(1))) void*)gp,
                (__attribute__((address_space(3))) void*)(dst + i * 4096 + ldsWaveOff),
                16, 0, 0);
        }
    };
    auto frag = [&](const char* src, int row, int chunk8) -> bf16x8 {
        return *reinterpret_cast<const bf16x8*>(src + row * 128 + ((chunk8 ^ xr) << 4));
    };

    // ---- Phase A: load 128 Q-rows x 256 dims into registers (once) ----
    bf16x8 qf[8][4];   // [kstep*2+kk][j]
    stage(qb, qbase, 0, b0);
    __syncthreads();
    #pragma unroll
    for (int c = 0; c < 4; ++c) {
        if (c < 3) stage(qb, qbase, (c + 1) * 64, (c & 1) ? b0 : b1);
        else       stage(kb, kstrip0, 0, b0);          // prologue of K stream
        const char* src = (c & 1) ? b1 : b0;
        #pragma unroll
        for (int kk = 0; kk < 2; ++kk)
            #pragma unroll
            for (int j = 0; j < 4; ++j)
                qf[c * 2 + kk][j] = frag(src, waveQ * 64 + j * 16 + r16, kk * 4 + g);
        __syncthreads();   // (also drains the K prologue load -- one-time cost)
    }

    // ---- Phase B: 32-step K stream, counted-vmcnt double-buffer pipeline ----
    f32x4 acc[4][4] = {};
    float ssum[4] = {0.f, 0.f, 0.f, 0.f};

    #pragma unroll 1
    for (int chunk = 0; chunk < 8; ++chunk) {
        const int kbase_c = kstrip0 + chunk * 128;
        #pragma unroll
        for (int kstep = 0; kstep < 4; ++kstep) {
            // stage next step into the other buffer (issue-early, stays in flight)
            if (kstep < 3) {
                stage(kb, kbase_c, (kstep + 1) * 64, (kstep & 1) ? b0 : b1);
            } else if (chunk < 7) {
                stage(kb, kbase_c + 128, 0, b0);       // next chunk, kstep 0
            }
            // wait ONLY for the previous step's 4 loads (ours for buf[cur])
            if (chunk == 7 && kstep == 3) {
                asm volatile("s_waitcnt vmcnt(0)" ::: "memory");
            } else {
                asm volatile("s_waitcnt vmcnt(4)" ::: "memory");
            }
            __builtin_amdgcn_s_barrier();              // raw: no vmcnt drain
            __builtin_amdgcn_sched_barrier(0);

            const char* src = (kstep & 1) ? b1 : b0;
            #pragma unroll
            for (int kk = 0; kk < 2; ++kk) {
                bf16x8 a[4];
                #pragma unroll
                for (int i = 0; i < 4; ++i)
                    a[i] = frag(src, waveK * 64 + i * 16 + r16, kk * 4 + g);
                #pragma unroll
                for (int i = 0; i < 4; ++i)
                    #pragma unroll
                    for (int j = 0; j < 4; ++j)
                        acc[i][j] = __builtin_amdgcn_mfma_f32_16x16x32_bf16(
                            a[i], qf[kstep * 2 + kk][j], acc[i][j], 0, 0, 0);
            }
            if (kstep == 3) {
                // ---- fused epilogue for this chunk (registers only) ----
                const bool diag = (strip * 8 + chunk) == qtile;
                if (diag) {
                    #pragma unroll
                    for (int j = 0; j < 4; ++j) {
                        const int grow = qbase + waveQ * 64 + j * 16 + r16;
                        float s = 0.f;
                        #pragma unroll
                        for (int i = 0; i < 4; ++i) {
                            const int colb = kbase_c + waveK * 64 + i * 16 + g * 4;
                            #pragma unroll
                            for (int reg = 0; reg < 4; ++reg) {
                                float e = exp2f(fmaf(acc[i][j][reg], C1, C0));
                                if (grow == colb + reg) e = 0.f;
                                s += e;
                            }
                        }
                        ssum[j] += s;
                    }
                } else {
                    #pragma unroll
                    for (int j = 0; j < 4; ++j) {
                        float s = 0.f;
                        #pragma unroll
                        for (int i = 0; i < 4; ++i)
                            #pragma unroll
                            for (int reg = 0; reg < 4; ++reg)
                                s += exp2f(fmaf(acc[i][j][reg], C1, C0));
                        ssum[j] += s;
                    }
                }
                #pragma unroll
                for (int i = 0; i < 4; ++i)
                    #pragma unroll
                    for (int j = 0; j < 4; ++j)
                        acc[i][j] = f32x4{0.f, 0.f, 0.f, 0.f};
            }
            __builtin_amdgcn_s_barrier();   // all reads of buf[cur] done -> next
                                            // step may overwrite buf[cur^1]
        }
    }

    // ---- block reduction: combine g-groups and waveK halves ----
    #pragma unroll
    for (int j = 0; j < 4; ++j) {
        float s = ssum[j];
        s += __shfl_xor(s, 16, 64);
        s += __shfl_xor(s, 32, 64);
        if (g == 0) redS[(waveQ * 64 + j * 16 + r16) * 2 + waveK] = s;
    }
    __syncthreads();
    if (tid < 128)
        ps[(size_t)(qbase + tid) * 8 + strip] = redS[tid * 2] + redS[tid * 2 + 1];
}

// ---------------- Kernel 3: combine 8 strip partials -> loss ----------------
__global__ __launch_bounds__(256) void finalize_kernel(
    const float* __restrict__ ps, const float* __restrict__ lposT,
    float* __restrict__ out) {
    const int row = blockIdx.x * 256 + threadIdx.x;
    const float4 p0 = *reinterpret_cast<const float4*>(ps + (size_t)row * 8);
    const float4 p1 = *reinterpret_cast<const float4*>(ps + (size_t)row * 8 + 4);
    float S = p0.x + p0.y + p0.z + p0.w + p1.x + p1.y + p1.z + p1.w;
    const float lp = lposT[row];
    S += __expf(lp - M0);
    out[row] = M0 + logf(S) - lp;
}

extern "C" void kernel_launch(void* const* d_in, const int* in_sizes, int n_in,
                              void* d_out, int out_size, void* d_ws, size_t ws_size,
                              hipStream_t stream) {
    const float* q = (const float*)d_in[0];
    const float* k = (const float*)d_in[1];
    float* out = (float*)d_out;

    char* ws = (char*)d_ws;
    unsigned short* qb  = (unsigned short*)(ws);                      // 4 MB
    unsigned short* kb  = (unsigned short*)(ws + (4u << 20));         // 4 MB
    float*          lpt = (float*)(ws + (8u << 20));                  // 32 KB
    float*          ps  = (float*)(ws + (8u << 20) + (32u << 10));    // 256 KB

    prep_kernel<<<N_ROWS / 4, 256, 0, stream>>>(q, k, qb, kb, lpt);
    dim3 grid(8, 64);   // x = strip (-> XCD), y = Q-tile
    gemm_lse_kernel<<<grid, 256, 0, stream>>>(qb, kb, ps);
    finalize_kernel<<<N_ROWS / 256, 256, 0, stream>>>(ps, lpt, out);
}

// Round 5
// 51.024 us; speedup vs baseline: 1.0944x; 1.0944x over previous
//
#include <hip/hip_runtime.h>
#include <stdint.h>

#define N_ROWS 8192
#define DIM 256

constexpr float INV_T  = 1.0f / 0.07f;
constexpr float M0     = 1.0f / 0.07f;             // fixed LSE max: |cos| <= ~1
constexpr float LOG2E  = 1.44269504088896f;
constexpr float C1     = INV_T * LOG2E;            // exp arg scale (exp2 domain)
constexpr float C0     = -M0 * LOG2E;              // exp arg bias

typedef __bf16 bf16x8 __attribute__((ext_vector_type(8)));
typedef float  f32x4  __attribute__((ext_vector_type(4)));

__device__ inline unsigned short f32_to_bf16(float f) {
    union { float f; uint32_t u; } v; v.f = f;
    uint32_t u = v.u;
    u += 0x7FFFu + ((u >> 16) & 1u);   // round-to-nearest-even
    return (unsigned short)(u >> 16);
}

// Raw hardware exp2: args are in [-28.6, 0.03] (normal range), ~1 ulp.
// Pure asm (no volatile/clobber) so the scheduler can move/CSE it freely.
__device__ inline float fast_exp2(float x) {
    float r;
    asm("v_exp_f32 %0, %1" : "=v"(r) : "v"(x));
    return r;
}

// ---------------- Kernel 1: normalize rows -> bf16, l_pos ----------------
__global__ __launch_bounds__(256) void prep_kernel(
    const float* __restrict__ q, const float* __restrict__ k,
    unsigned short* __restrict__ qb, unsigned short* __restrict__ kb,
    float* __restrict__ lposT) {
    const int wid  = threadIdx.x >> 6;
    const int lane = threadIdx.x & 63;
    const int row  = blockIdx.x * 4 + wid;

    const float4 qv = *reinterpret_cast<const float4*>(q + (size_t)row * DIM + lane * 4);
    const float4 kv = *reinterpret_cast<const float4*>(k + (size_t)row * DIM + lane * 4);

    float qq = qv.x*qv.x + qv.y*qv.y + qv.z*qv.z + qv.w*qv.w;
    float kk = kv.x*kv.x + kv.y*kv.y + kv.z*kv.z + kv.w*kv.w;
    float qk = qv.x*kv.x + qv.y*kv.y + qv.z*kv.z + qv.w*kv.w;

    #pragma unroll
    for (int off = 32; off > 0; off >>= 1) {
        qq += __shfl_xor(qq, off, 64);
        kk += __shfl_xor(kk, off, 64);
        qk += __shfl_xor(qk, off, 64);
    }
    const float iq = 1.0f / sqrtf(qq);
    const float ik = 1.0f / sqrtf(kk);

    ushort4 qs, ks;
    qs.x = f32_to_bf16(qv.x * iq); qs.y = f32_to_bf16(qv.y * iq);
    qs.z = f32_to_bf16(qv.z * iq); qs.w = f32_to_bf16(qv.w * iq);
    ks.x = f32_to_bf16(kv.x * ik); ks.y = f32_to_bf16(kv.y * ik);
    ks.z = f32_to_bf16(kv.z * ik); ks.w = f32_to_bf16(kv.w * ik);
    *reinterpret_cast<ushort4*>(qb + (size_t)row * DIM + lane * 4) = qs;
    *reinterpret_cast<ushort4*>(kb + (size_t)row * DIM + lane * 4) = ks;

    if (lane == 0) lposT[row] = qk * iq * ik * INV_T;
}

// ---------------- Kernel 2: persistent K-strip GEMM + fused exp-sum ----------
// A = K rows, B = Q rows (swapped) -> D col = lane&15 = Q row (lane-local sums).
// 16 strips x 512 K-rows (4 chunks x 4 ksteps). Counted-vmcnt 2-barrier steps.
// Chunk epilogue DEFERRED one chunk (runs at next chunk's kstep 0, independent
// of in-flight MFMAs -> VALU overlaps matrix pipe).
__global__ __launch_bounds__(256, 2) void gemm_lse_kernel(
    const unsigned short* __restrict__ qb, const unsigned short* __restrict__ kb,
    float* __restrict__ ps) {
    __shared__ char lds[2 * 16384 + 1024];
    char* const b0 = lds;
    char* const b1 = lds + 16384;
    float* const redS = (float*)(lds + 32768);

    const int tid   = threadIdx.x;
    const int lane  = tid & 63;
    const int wid   = tid >> 6;
    const int waveQ = wid & 1;       // Q half (B operand / D cols)
    const int waveK = wid >> 1;      // K half (A operand / D rows)
    const int g     = lane >> 4;
    const int r16   = lane & 15;
    const int xr    = r16 & 7;

    const int strip   = blockIdx.x;        // 0..15 (x%8 == XCD by dispatch order)
    const int qtile   = blockIdx.y;        // 0..63
    const int qbase   = qtile * 128;
    const int kstrip0 = strip * 512;

    // staging map: thread t -> row t/8, pre-swizzled 16B slot (t%8)^(row&7)
    const int srow  = tid >> 3;
    const int sslot = (tid & 7) ^ (srow & 7);
    const int ldsWaveOff = wid * 1024;     // wave-uniform LDS sub-base

    auto stage = [&](const unsigned short* base, int row0, int k0, char* dst) {
        #pragma unroll
        for (int i = 0; i < 4; ++i) {
            const unsigned short* gp = base + (size_t)(row0 + i * 32 + srow) * DIM + k0 + sslot * 8;
            __builtin_amdgcn_global_load_lds(
                (const __attribute__((address_space(1))) void*)gp,
                (__attribute__((address_space(3))) void*)(dst + i * 4096 + ldsWaveOff),
                16, 0, 0);
        }
    };
    auto frag = [&](const char* src, int row, int chunk8) -> bf16x8 {
        return *reinterpret_cast<const bf16x8*>(src + row * 128 + ((chunk8 ^ xr) << 4));
    };

    // ---- Phase A: load 128 Q-rows x 256 dims into registers (once) ----
    bf16x8 qf[8][4];   // [kstep*2+kk][j]
    stage(qb, qbase, 0, b0);
    __syncthreads();
    #pragma unroll
    for (int c = 0; c < 4; ++c) {
        if (c < 3) stage(qb, qbase, (c + 1) * 64, (c & 1) ? b0 : b1);
        else       stage(kb, kstrip0, 0, b0);          // prologue of K stream
        const char* src = (c & 1) ? b1 : b0;
        #pragma unroll
        for (int kk = 0; kk < 2; ++kk)
            #pragma unroll
            for (int j = 0; j < 4; ++j)
                qf[c * 2 + kk][j] = frag(src, waveQ * 64 + j * 16 + r16, kk * 4 + g);
        __syncthreads();   // (also drains the K prologue load -- one-time cost)
    }

    // ---- Phase B: 16-step K stream, counted-vmcnt double-buffer pipeline ----
    f32x4 acc[4][4] = {};
    float ssum[4] = {0.f, 0.f, 0.f, 0.f};

    // Deferred epilogue: consume acc for chunkIdx, then zero acc (reg-only).
    auto epilogue = [&](int chunkIdx) {
        const int kbase_c = kstrip0 + chunkIdx * 128;
        if ((strip * 4 + chunkIdx) == qtile) {
            #pragma unroll
            for (int j = 0; j < 4; ++j) {
                const int grow = qbase + waveQ * 64 + j * 16 + r16;
                float s = 0.f;
                #pragma unroll
                for (int i = 0; i < 4; ++i) {
                    const int colb = kbase_c + waveK * 64 + i * 16 + g * 4;
                    #pragma unroll
                    for (int reg = 0; reg < 4; ++reg) {
                        float e = fast_exp2(fmaf(acc[i][j][reg], C1, C0));
                        if (grow == colb + reg) e = 0.f;
                        s += e;
                    }
                }
                ssum[j] += s;
            }
        } else {
            #pragma unroll
            for (int j = 0; j < 4; ++j) {
                float s = 0.f;
                #pragma unroll
                for (int i = 0; i < 4; ++i)
                    #pragma unroll
                    for (int reg = 0; reg < 4; ++reg)
                        s += fast_exp2(fmaf(acc[i][j][reg], C1, C0));
                ssum[j] += s;
            }
        }
        #pragma unroll
        for (int i = 0; i < 4; ++i)
            #pragma unroll
            for (int j = 0; j < 4; ++j)
                acc[i][j] = f32x4{0.f, 0.f, 0.f, 0.f};
    };

    #pragma unroll 1
    for (int chunk = 0; chunk < 4; ++chunk) {
        const int kbase_c = kstrip0 + chunk * 128;
        #pragma unroll
        for (int kstep = 0; kstep < 4; ++kstep) {
            // stage next step into the other buffer (issue-early, stays in flight)
            if (kstep < 3) {
                stage(kb, kbase_c, (kstep + 1) * 64, (kstep & 1) ? b0 : b1);
            } else if (chunk < 3) {
                stage(kb, kbase_c + 128, 0, b0);       // next chunk, kstep 0
            }
            // wait ONLY for the previous step's 4 loads (ours for buf[cur])
            if (chunk == 3 && kstep == 3) {
                asm volatile("s_waitcnt vmcnt(0)" ::: "memory");
            } else {
                asm volatile("s_waitcnt vmcnt(4)" ::: "memory");
            }
            __builtin_amdgcn_s_barrier();              // raw: no vmcnt drain
            __builtin_amdgcn_sched_barrier(0);

            // deferred epilogue of the PREVIOUS chunk: independent of this
            // step's MFMAs -> scheduler interleaves VALU under matrix pipe
            if (kstep == 0 && chunk > 0) epilogue(chunk - 1);

            const char* src = (kstep & 1) ? b1 : b0;
            #pragma unroll
            for (int kk = 0; kk < 2; ++kk) {
                bf16x8 a[4];
                #pragma unroll
                for (int i = 0; i < 4; ++i)
                    a[i] = frag(src, waveK * 64 + i * 16 + r16, kk * 4 + g);
                #pragma unroll
                for (int i = 0; i < 4; ++i)
                    #pragma unroll
                    for (int j = 0; j < 4; ++j)
                        acc[i][j] = __builtin_amdgcn_mfma_f32_16x16x32_bf16(
                            a[i], qf[kstep * 2 + kk][j], acc[i][j], 0, 0, 0);
            }
            __builtin_amdgcn_s_barrier();   // all reads of buf[cur] done -> next
                                            // step may overwrite buf[cur^1]
        }
    }
    epilogue(3);   // last chunk

    // ---- block reduction: combine g-groups and waveK halves ----
    #pragma unroll
    for (int j = 0; j < 4; ++j) {
        float s = ssum[j];
        s += __shfl_xor(s, 16, 64);
        s += __shfl_xor(s, 32, 64);
        if (g == 0) redS[(waveQ * 64 + j * 16 + r16) * 2 + waveK] = s;
    }
    __syncthreads();
    if (tid < 128)
        ps[(size_t)(qbase + tid) * 16 + strip] = redS[tid * 2] + redS[tid * 2 + 1];
}

// ---------------- Kernel 3: combine 16 strip partials -> loss ----------------
__global__ __launch_bounds__(256) void finalize_kernel(
    const float* __restrict__ ps, const float* __restrict__ lposT,
    float* __restrict__ out) {
    const int row = blockIdx.x * 256 + threadIdx.x;
    float S = 0.f;
    #pragma unroll
    for (int c = 0; c < 4; ++c) {
        const float4 p = *reinterpret_cast<const float4*>(ps + (size_t)row * 16 + c * 4);
        S += p.x + p.y + p.z + p.w;
    }
    const float lp = lposT[row];
    S += __expf(lp - M0);
    out[row] = M0 + logf(S) - lp;
}

extern "C" void kernel_launch(void* const* d_in, const int* in_sizes, int n_in,
                              void* d_out, int out_size, void* d_ws, size_t ws_size,
                              hipStream_t stream) {
    const float* q = (const float*)d_in[0];
    const float* k = (const float*)d_in[1];
    float* out = (float*)d_out;

    char* ws = (char*)d_ws;
    unsigned short* qb  = (unsigned short*)(ws);                      // 4 MB
    unsigned short* kb  = (unsigned short*)(ws + (4u << 20));         // 4 MB
    float*          lpt = (float*)(ws + (8u << 20));                  // 32 KB
    float*          ps  = (float*)(ws + (8u << 20) + (32u << 10));    // 512 KB

    prep_kernel<<<N_ROWS / 4, 256, 0, stream>>>(q, k, qb, kb, lpt);
    dim3 grid(16, 64);   // x = strip (x%8 -> XCD), y = Q-tile
    gemm_lse_kernel<<<grid, 256, 0, stream>>>(qb, kb, ps);
    finalize_kernel<<<N_ROWS / 256, 256, 0, stream>>>(ps, lpt, out);
}